// Round 5
// baseline (353.516 us; speedup 1.0000x reference)
//
#include <hip/hip_runtime.h>
#include <hip/hip_bf16.h>

// ---------------------------------------------------------------------------
// MVoT token processor: out = hidden + MLP_{type}(LN(hidden)), type in {0,1}
// Partition tokens by type -> dense bf16 MFMA GEMMs (half the reference FLOPs).
// GEMM: 256x256, BK=64, 8 waves, 4 phases/K-tile, asm-lowered inner loop with
// SOFTWARE-PIPELINED ds_reads: reads issued >=1 phase before MFMA use, waits
// are COUNTED lgkmcnt(N) draining only older reads (R4 drained everything
// per-phase -> no read/MFMA overlap -> ~1450cyc/phase).
// ---------------------------------------------------------------------------

#define H_DIM 2048

typedef __attribute__((ext_vector_type(8))) short s16x8;   // 8 bf16 (4 VGPRs)
typedef __attribute__((ext_vector_type(4))) float f32x4;   // MFMA accumulator
typedef __attribute__((ext_vector_type(4))) int   i32x4;   // asm ds_read dst

typedef __attribute__((address_space(1))) const unsigned int gu32;
typedef __attribute__((address_space(3))) unsigned int lu32;
typedef __attribute__((address_space(3))) short lds_s;

__device__ __forceinline__ void load_lds16(const void* g, void* l) {
  // async global->LDS, 16B per lane; LDS dest = wave-uniform base + lane*16
  __builtin_amdgcn_global_load_lds((gu32*)g, (lu32*)l, 16, 0, 0);
}

__device__ __forceinline__ s16x8 asbf(i32x4 v) {
  union { i32x4 i; s16x8 s; } u; u.i = v; return u.s;
}

// ---------------------------------------------------------------------------
// Partition: stable scan of token_type_ids. text (type==0) first, padded to
// 256 rows (BM), then image (type==1), padded to 256. Single block.
// ctrl: [0]=Mt [1]=Mt_pad [2]=Mi [3]=Mi_pad [4]=total_rows
// ---------------------------------------------------------------------------
__global__ __launch_bounds__(256) void partition_kernel(
    const int* __restrict__ tt, int T, int* __restrict__ ctrl,
    int* __restrict__ pos, int* __restrict__ rowid) {
  __shared__ int psum[256];
  const int tid = threadIdx.x;
  const int npt = T >> 8;
  const int base = tid * npt;
  int cnt = 0;
  for (int i = 0; i < npt; ++i) cnt += (tt[base + i] == 0);
  psum[tid] = cnt;
  __syncthreads();
  for (int off = 1; off < 256; off <<= 1) {
    int v = psum[tid];
    int add = (tid >= off) ? psum[tid - off] : 0;
    __syncthreads();
    psum[tid] = v + add;
    __syncthreads();
  }
  const int Mt = psum[255];
  const int Mt_pad = (Mt + 255) & ~255;
  int tpos = psum[tid] - cnt;
  int ipos = base - tpos;
  for (int i = 0; i < npt; ++i) {
    const int tok = base + i;
    int p;
    if (tt[tok] == 0) p = tpos++;
    else              p = Mt_pad + ipos++;
    pos[tok] = p;
    rowid[p] = tok;
  }
  const int Mi = T - Mt;
  const int Mi_pad = (Mi + 255) & ~255;
  for (int g = Mt + tid; g < Mt_pad; g += 256) rowid[g] = -1;
  for (int g = Mt_pad + Mi + tid; g < Mt_pad + Mi_pad; g += 256) rowid[g] = -1;
  if (tid == 0) {
    ctrl[0] = Mt; ctrl[1] = Mt_pad; ctrl[2] = Mi; ctrl[3] = Mi_pad;
    ctrl[4] = Mt_pad + Mi_pad;
  }
}

// ---------------------------------------------------------------------------
// Weight transpose + fp32->bf16: W[k][n] -> WT[n][k] (B^T layout for GEMM)
// ---------------------------------------------------------------------------
__global__ __launch_bounds__(256) void transpose_to_bf16(
    const float* __restrict__ W, __hip_bfloat16* __restrict__ WT) {
  __shared__ float tile[32][33];
  const int bx = blockIdx.x, by = blockIdx.y;
  const int tid = threadIdx.x;
  const int r = tid >> 3, c4 = (tid & 7) * 4;
  const float4 v = *(const float4*)(W + (size_t)(by * 32 + r) * H_DIM + bx * 32 + c4);
  tile[r][c4 + 0] = v.x; tile[r][c4 + 1] = v.y;
  tile[r][c4 + 2] = v.z; tile[r][c4 + 3] = v.w;
  __syncthreads();
  union { ushort u[4]; ushort4 v4; } pk;
#pragma unroll
  for (int j = 0; j < 4; ++j) {
    __hip_bfloat16 h = __float2bfloat16(tile[c4 + j][r]);
    pk.u[j] = *(const ushort*)&h;
  }
  *(ushort4*)(WT + (size_t)(bx * 32 + r) * H_DIM + by * 32 + c4) = pk.v4;
}

// ---------------------------------------------------------------------------
// LayerNorm (fp32) -> bf16, scatter row to its gathered position.
// ---------------------------------------------------------------------------
__global__ __launch_bounds__(256) void ln_scatter_kernel(
    const float* __restrict__ X, const float* __restrict__ gamma,
    const float* __restrict__ beta, const int* __restrict__ pos,
    __hip_bfloat16* __restrict__ XG) {
  const int t = blockIdx.x, tid = threadIdx.x;
  const float* row = X + (size_t)t * H_DIM;
  float x[8];
  {
    float4 v0 = *(const float4*)(row + tid * 8);
    float4 v1 = *(const float4*)(row + tid * 8 + 4);
    x[0] = v0.x; x[1] = v0.y; x[2] = v0.z; x[3] = v0.w;
    x[4] = v1.x; x[5] = v1.y; x[6] = v1.z; x[7] = v1.w;
  }
  float s = 0.f, q = 0.f;
#pragma unroll
  for (int j = 0; j < 8; ++j) { s += x[j]; q += x[j] * x[j]; }
#pragma unroll
  for (int off = 32; off > 0; off >>= 1) {
    s += __shfl_down(s, off);
    q += __shfl_down(q, off);
  }
  __shared__ float ls[4], lq[4];
  if ((tid & 63) == 0) { ls[tid >> 6] = s; lq[tid >> 6] = q; }
  __syncthreads();
  const float S = ls[0] + ls[1] + ls[2] + ls[3];
  const float Q = lq[0] + lq[1] + lq[2] + lq[3];
  const float mu = S * (1.0f / H_DIM);
  const float var = Q * (1.0f / H_DIM) - mu * mu;
  const float rstd = rsqrtf(var + 1e-12f);
  const int p = pos[t];
  float4 g0 = *(const float4*)(gamma + tid * 8);
  float4 g1 = *(const float4*)(gamma + tid * 8 + 4);
  float4 b0 = *(const float4*)(beta + tid * 8);
  float4 b1 = *(const float4*)(beta + tid * 8 + 4);
  float g[8] = {g0.x, g0.y, g0.z, g0.w, g1.x, g1.y, g1.z, g1.w};
  float b[8] = {b0.x, b0.y, b0.z, b0.w, b1.x, b1.y, b1.z, b1.w};
  union { ushort u[8]; int4 v; } pk;
#pragma unroll
  for (int j = 0; j < 8; ++j) {
    float y = (x[j] - mu) * rstd * g[j] + b[j];
    __hip_bfloat16 h = __float2bfloat16(y);
    pk.u[j] = *(const ushort*)&h;
  }
  *(int4*)(XG + (size_t)p * H_DIM + tid * 8) = pk.v;
}

// --- asm helpers for the GEMM inner loop -----------------------------------
#define DSRD(dst, addr, OFF) \
  asm volatile("ds_read_b128 %0, %1 offset:" OFF : "=v"(dst) : "v"(addr))
#define PBAR asm volatile("s_barrier" ::: "memory")
#define SB0  __builtin_amdgcn_sched_barrier(0)
#define WAIT_LGKM(N) do { \
  asm volatile("s_waitcnt lgkmcnt(" #N ")" ::: "memory"); SB0; } while (0)

// ---------------------------------------------------------------------------
// Pipelined 4-phase GEMM. 512 thr = 8 waves, wm=w>>2, wn=w&3.
// Per-wave output 128x64 = acc[8][4] frags of 16x16x32, BK=64 (2 k-slices).
// LDS: Alds/Blds [2 buf][2 half: 128 rows][128*64], XOR swizzle on 8-elem
// granules (granule g of row r at position g^(r&7)); staging realizes the
// swizzle by pre-swizzling the GLOBAL source (linear LDS dest, rule #21).
//
// Read pipeline (per K-tile t, buf C; quadrants Q1..Q4 = MFMA clusters):
//  P1: issue A_lo(8), B_lo(4), B_hi(4); stage A(t+1)h0; bar;
//      lgkmcnt(4)  -> drains A_lo+B_lo, B_hi STAYS IN FLIGHT; Q1(a_lo,b_lo)
//  P2: stage A(t+1)h1; bar; lgkmcnt(0) [B_hi, 1 phase cover]; Q2(a_lo,b_hi)
//  P3: issue A_hi(8) into a[] (a_lo dead after Q2); stage B(t+2)h0; bar;
//      lgkmcnt(0); Q3(a_hi,b_hi)
//  P4: stage B(t+2)h1; vmcnt(4) [drains A(t+1),B(t+1); leaves B(t+2)];
//      bar; NO lgkm wait; Q4(a_hi,b_lo); bar
// FIFO counts verified; DS ops retire in order. Cross-wave LDS hazards: every
// stage lands >=1 barrier after the target region's last reads drained; every
// read follows all-waves vmcnt(4)+barrier for its staged data.
// ---------------------------------------------------------------------------
template <int EPI>
__global__ __launch_bounds__(512, 2) void gemm8_kernel(
    const __hip_bfloat16* __restrict__ A,
    const __hip_bfloat16* __restrict__ WTt, const __hip_bfloat16* __restrict__ WTi,
    const float* __restrict__ bt, const float* __restrict__ bi,
    const int* __restrict__ ctrl, const int* __restrict__ rowid,
    __hip_bfloat16* __restrict__ Hout,
    const float* __restrict__ resid, float* __restrict__ Out) {
  constexpr int K = H_DIM;
  constexpr int NT = K / 64;            // 32 K-tiles
  const int Mt_pad = ctrl[1];
  const int total = ctrl[4];
  const int m0 = blockIdx.x * 256;      // M-tiles on x: consecutive blocks
  if (m0 >= total) return;              // share the same B panel (XCD L2 reuse)
  const int n0 = blockIdx.y * 256;
  const bool is_text = (m0 < Mt_pad);
  const short* Ag = (const short*)A;
  const short* Bg = (const short*)(is_text ? WTt : WTi);
  const float* bias = is_text ? bt : bi;

  __shared__ __align__(16) short Alds[2][2][8192];   // [buf][half:128 rows][128*64]
  __shared__ __align__(16) short Blds[2][2][8192];

  const int tid = threadIdx.x;
  const int w = tid >> 6, l = tid & 63;
  const int wm = w >> 2, wn = w & 3;

  // staging lane constants (pre-swizzled global source, linear LDS dest)
  const int srow8 = l >> 3;                  // 0..7
  const int scol8 = ((l & 7) ^ srow8) * 8;   // bf16 k-offset within row

  auto stageA = [&](int bI, int h, int kk) {
#pragma unroll
    for (int c = 0; c < 2; ++c) {
      const short* src = Ag + (size_t)(m0 + h * 128 + c * 64 + w * 8 + srow8) * K + kk + scol8;
      load_lds16(src, &Alds[bI][h][c * 4096 + w * 512]);
    }
  };
  auto stageB = [&](int bI, int h, int kk) {
#pragma unroll
    for (int c = 0; c < 2; ++c) {
      const short* src = Bg + (size_t)(n0 + h * 128 + c * 64 + w * 8 + srow8) * K + kk + scol8;
      load_lds16(src, &Blds[bI][h][c * 4096 + w * 512]);
    }
  };

  // read offsets within a half (elems): row r16, granule (ks*4 + l>>4) ^ (l&7)
  const int r16 = l & 15;
  int off2[2];
#pragma unroll
  for (int ks = 0; ks < 2; ++ks)
    off2[ks] = r16 * 64 + (((ks * 4 + (l >> 4)) ^ (l & 7)) * 8);

  // byte-address base registers for asm ds_read (per buffer, per k-slice)
  const unsigned aBase = (unsigned)(uintptr_t)(lds_s*)&Alds[0][0][0];
  const unsigned bBase = (unsigned)(uintptr_t)(lds_s*)&Blds[0][0][0];
  unsigned ardA[2][2], ardB[2][2];
#pragma unroll
  for (int bI = 0; bI < 2; ++bI)
#pragma unroll
    for (int ks = 0; ks < 2; ++ks) {
      ardA[bI][ks] = aBase + bI * 32768u + (unsigned)(wm * 16384 + off2[ks] * 2);
      ardB[bI][ks] = bBase + bI * 32768u +
                     (unsigned)((wn >> 1) * 16384 + ((wn & 1) * 4096 + off2[ks]) * 2);
    }

  i32x4 a[4][2], b[4][2];
  f32x4 acc[8][4];
  const f32x4 zero = {0.f, 0.f, 0.f, 0.f};
#pragma unroll
  for (int i = 0; i < 8; ++i)
#pragma unroll
    for (int j = 0; j < 4; ++j) acc[i][j] = zero;

  auto mfmaQ = [&](int fmBase, int fnBase) {   // 16 MFMA
#pragma unroll
    for (int fm = 0; fm < 4; ++fm)
#pragma unroll
      for (int fn = 0; fn < 2; ++fn)
#pragma unroll
        for (int ks = 0; ks < 2; ++ks)
          acc[fmBase + fm][fnBase + fn] = __builtin_amdgcn_mfma_f32_16x16x32_bf16(
              asbf(a[fm][ks]), asbf(b[fnBase + fn][ks]),
              acc[fmBase + fm][fnBase + fn], 0, 0, 0);
  };

#define TILE(C) do {                                                          \
    /* P1: issue A_lo(8) + B_lo(4) + B_hi(4); stage A(t+1)h0 */               \
    DSRD(a[0][0], ardA[C][0], "0");     DSRD(a[0][1], ardA[C][1], "0");       \
    DSRD(a[1][0], ardA[C][0], "2048");  DSRD(a[1][1], ardA[C][1], "2048");    \
    DSRD(a[2][0], ardA[C][0], "4096");  DSRD(a[2][1], ardA[C][1], "4096");    \
    DSRD(a[3][0], ardA[C][0], "6144");  DSRD(a[3][1], ardA[C][1], "6144");    \
    DSRD(b[0][0], ardB[C][0], "0");     DSRD(b[0][1], ardB[C][1], "0");       \
    DSRD(b[1][0], ardB[C][0], "2048");  DSRD(b[1][1], ardB[C][1], "2048");    \
    DSRD(b[2][0], ardB[C][0], "4096");  DSRD(b[2][1], ardB[C][1], "4096");    \
    DSRD(b[3][0], ardB[C][0], "6144");  DSRD(b[3][1], ardB[C][1], "6144");    \
    stageA(C ^ 1, 0, _kA);                                                    \
    PBAR;                                                                     \
    WAIT_LGKM(4); /* drains A_lo+B_lo; B_hi in flight through Q1 */           \
    __builtin_amdgcn_s_setprio(1); mfmaQ(0, 0); __builtin_amdgcn_s_setprio(0);\
    SB0; PBAR;                                                                \
    /* P2: no reads; stage A(t+1)h1 */                                        \
    stageA(C ^ 1, 1, _kA);                                                    \
    PBAR;                                                                     \
    WAIT_LGKM(0); /* B_hi, one full phase of cover */                         \
    __builtin_amdgcn_s_setprio(1); mfmaQ(0, 2); __builtin_amdgcn_s_setprio(0);\
    SB0; PBAR;                                                                \
    /* P3: issue A_hi(8) into a[] (a_lo dead); stage B(t+2)h0 */              \
    DSRD(a[0][0], ardA[C][0], "8192");  DSRD(a[0][1], ardA[C][1], "8192");    \
    DSRD(a[1][0], ardA[C][0], "10240"); DSRD(a[1][1], ardA[C][1], "10240");   \
    DSRD(a[2][0], ardA[C][0], "12288"); DSRD(a[2][1], ardA[C][1], "12288");   \
    DSRD(a[3][0], ardA[C][0], "14336"); DSRD(a[3][1], ardA[C][1], "14336");   \
    stageB(C, 0, _kB);                                                        \
    PBAR;                                                                     \
    WAIT_LGKM(0);                                                             \
    __builtin_amdgcn_s_setprio(1); mfmaQ(4, 2); __builtin_amdgcn_s_setprio(0);\
    SB0; PBAR;                                                                \
    /* P4: stage B(t+2)h1; counted vmcnt; NO lgkm wait */                     \
    stageB(C, 1, _kB);                                                        \
    asm volatile("s_waitcnt vmcnt(4)" ::: "memory");                          \
    PBAR; SB0;                                                                \
    __builtin_amdgcn_s_setprio(1); mfmaQ(4, 0); __builtin_amdgcn_s_setprio(0);\
    SB0; PBAR;                                                                \
  } while (0)

  // prologue: A(0), B(0) fully; then B(1) (newest 4 loads stay in flight)
  stageA(0, 0, 0); stageA(0, 1, 0);
  stageB(0, 0, 0); stageB(0, 1, 0);
  stageB(1, 0, 64); stageB(1, 1, 64);
  asm volatile("s_waitcnt vmcnt(4)" ::: "memory");
  PBAR;

  int _kA, _kB;
  for (int t = 0; t < NT; t += 2) {
    _kA = (t + 1 < NT ? t + 1 : NT - 1) * 64;
    _kB = (t + 2 < NT ? t + 2 : NT - 1) * 64;
    TILE(0);
    _kA = (t + 2 < NT ? t + 2 : NT - 1) * 64;
    _kB = (t + 3 < NT ? t + 3 : NT - 1) * 64;
    TILE(1);
  }
#undef TILE
  asm volatile("s_waitcnt vmcnt(0) lgkmcnt(0)" ::: "memory");

  // epilogue: C/D layout col=lane&15, row=(lane>>4)*4+i
  const int r4base = (l >> 4) * 4;
  if (EPI == 0) {
    float bb[4];
#pragma unroll
    for (int fn = 0; fn < 4; ++fn) bb[fn] = bias[n0 + wn * 64 + fn * 16 + r16];
#pragma unroll
    for (int fm = 0; fm < 8; ++fm) {
      const int grow = m0 + wm * 128 + fm * 16 + r4base;
#pragma unroll
      for (int fn = 0; fn < 4; ++fn) {
        const int gcol = n0 + wn * 64 + fn * 16 + r16;
        f32x4 v = acc[fm][fn];
#pragma unroll
        for (int i = 0; i < 4; ++i) {
          float z = v[i] + bb[fn];
          float ge = 0.5f * z * (1.0f + erff(z * 0.70710678118654752f));
          Hout[(size_t)(grow + i) * K + gcol] = __float2bfloat16(ge);
        }
      }
    }
  } else {
    float bb[4];
#pragma unroll
    for (int fn = 0; fn < 4; ++fn) bb[fn] = bias[n0 + wn * 64 + fn * 16 + r16];
#pragma unroll
    for (int fm = 0; fm < 8; ++fm) {
      const int grow = m0 + wm * 128 + fm * 16 + r4base;
      int rid[4];
#pragma unroll
      for (int i = 0; i < 4; ++i) rid[i] = rowid[grow + i];
#pragma unroll
      for (int fn = 0; fn < 4; ++fn) {
        const int gcol = n0 + wn * 64 + fn * 16 + r16;
        f32x4 v = acc[fm][fn];
#pragma unroll
        for (int i = 0; i < 4; ++i) {
          if (rid[i] >= 0) {
            const size_t o = (size_t)rid[i] * K + gcol;
            Out[o] = resid[o] + v[i] + bb[fn];
          }
        }
      }
    }
  }
}

// ---------------------------------------------------------------------------
extern "C" void kernel_launch(void* const* d_in, const int* in_sizes, int n_in,
                              void* d_out, int out_size, void* d_ws, size_t ws_size,
                              hipStream_t stream) {
  const float* hidden = (const float*)d_in[0];
  const int*   tt     = (const int*)d_in[1];
  const float* gamma  = (const float*)d_in[2];
  const float* beta   = (const float*)d_in[3];
  const float* tw1    = (const float*)d_in[4];
  const float* tb1    = (const float*)d_in[5];
  const float* tw2    = (const float*)d_in[6];
  const float* tb2    = (const float*)d_in[7];
  const float* iw1    = (const float*)d_in[8];
  const float* ib1    = (const float*)d_in[9];
  const float* iw2    = (const float*)d_in[10];
  const float* ib2    = (const float*)d_in[11];
  float* out = (float*)d_out;

  const int T = in_sizes[1];          // 8192 tokens
  const int K = H_DIM;
  const int maxtiles = T / 256 + 2;   // groups padded to 256 -> <= 34 tiles
  const int maxrows = maxtiles * 256;

  char* ws = (char*)d_ws;
  int* ctrl  = (int*)(ws);
  int* pos   = (int*)(ws + 4096);
  int* rowid = (int*)(ws + 65536);
  const size_t WOFF = 131072;
  const size_t WSZ = (size_t)K * K * sizeof(__hip_bfloat16);
  __hip_bfloat16* tw1T = (__hip_bfloat16*)(ws + WOFF);
  __hip_bfloat16* tw2T = (__hip_bfloat16*)(ws + WOFF + WSZ);
  __hip_bfloat16* iw1T = (__hip_bfloat16*)(ws + WOFF + 2 * WSZ);
  __hip_bfloat16* iw2T = (__hip_bfloat16*)(ws + WOFF + 3 * WSZ);
  __hip_bfloat16* xg   = (__hip_bfloat16*)(ws + WOFF + 4 * WSZ);
  __hip_bfloat16* hb   = xg + (size_t)maxrows * K;

  hipMemsetAsync(xg, 0, (size_t)maxrows * K * sizeof(__hip_bfloat16), stream);

  partition_kernel<<<1, 256, 0, stream>>>(tt, T, ctrl, pos, rowid);

  dim3 tg(K / 32, K / 32);
  transpose_to_bf16<<<tg, 256, 0, stream>>>(tw1, tw1T);
  transpose_to_bf16<<<tg, 256, 0, stream>>>(tw2, tw2T);
  transpose_to_bf16<<<tg, 256, 0, stream>>>(iw1, iw1T);
  transpose_to_bf16<<<tg, 256, 0, stream>>>(iw2, iw2T);

  ln_scatter_kernel<<<T, 256, 0, stream>>>(hidden, gamma, beta, pos, xg);

  dim3 gg(maxtiles, K / 256);
  gemm8_kernel<0><<<gg, 512, 0, stream>>>(xg, tw1T, iw1T, tb1, ib1, ctrl, rowid,
                                          hb, nullptr, nullptr);
  gemm8_kernel<1><<<gg, 512, 0, stream>>>(hb, tw2T, iw2T, tb2, ib2, ctrl, rowid,
                                          nullptr, hidden, out);
}

// Round 7
// 320.796 us; speedup vs baseline: 1.1020x; 1.1020x over previous
//
#include <hip/hip_runtime.h>
#include <hip/hip_bf16.h>

// ---------------------------------------------------------------------------
// MVoT token processor: out = hidden + MLP_{type}(LN(hidden)), type in {0,1}
// Partition tokens by type -> dense bf16 MFMA GEMMs (half the reference FLOPs).
// GEMM: R1's verified 4-wave 128x128 geometry (3-4 blocks/CU co-resident,
// ~125 regs/thread, NO launch-bounds cap -> no spill -> no asm-output-spill
// corruption like R6) + R6's trace-verified conflict-free macro-row XOR
// swizzle + 1 barrier/K-tile asm loop + XCD-grouped grid.
// ---------------------------------------------------------------------------

#define H_DIM 2048

typedef __attribute__((ext_vector_type(8))) short s16x8;   // 8 bf16 (4 VGPRs)
typedef __attribute__((ext_vector_type(4))) float f32x4;   // MFMA accumulator
typedef __attribute__((ext_vector_type(4))) int   i32x4;   // asm ds_read dst

typedef __attribute__((address_space(1))) const unsigned int gu32;
typedef __attribute__((address_space(3))) unsigned int lu32;
typedef __attribute__((address_space(3))) short lds_s;

__device__ __forceinline__ void load_lds16(const void* g, void* l) {
  // async global->LDS, 16B per lane; LDS dest = wave-uniform base + lane*16
  __builtin_amdgcn_global_load_lds((gu32*)g, (lu32*)l, 16, 0, 0);
}

__device__ __forceinline__ s16x8 asbf(i32x4 v) {
  union { i32x4 i; s16x8 s; } u; u.i = v; return u.s;
}

// ---------------------------------------------------------------------------
// Partition: stable scan of token_type_ids. text (type==0) first, padded to
// 128 rows (BM), then image (type==1), padded. Single block, deterministic.
// ctrl: [0]=Mt [1]=Mt_pad [2]=Mi [3]=Mi_pad [4]=total_rows
// ---------------------------------------------------------------------------
__global__ __launch_bounds__(256) void partition_kernel(
    const int* __restrict__ tt, int T, int* __restrict__ ctrl,
    int* __restrict__ pos, int* __restrict__ rowid) {
  __shared__ int psum[256];
  const int tid = threadIdx.x;
  const int npt = T >> 8;
  const int base = tid * npt;
  int cnt = 0;
  for (int i = 0; i < npt; ++i) cnt += (tt[base + i] == 0);
  psum[tid] = cnt;
  __syncthreads();
  for (int off = 1; off < 256; off <<= 1) {
    int v = psum[tid];
    int add = (tid >= off) ? psum[tid - off] : 0;
    __syncthreads();
    psum[tid] = v + add;
    __syncthreads();
  }
  const int Mt = psum[255];
  const int Mt_pad = (Mt + 127) & ~127;
  int tpos = psum[tid] - cnt;
  int ipos = base - tpos;
  for (int i = 0; i < npt; ++i) {
    const int tok = base + i;
    int p;
    if (tt[tok] == 0) p = tpos++;
    else              p = Mt_pad + ipos++;
    pos[tok] = p;
    rowid[p] = tok;
  }
  const int Mi = T - Mt;
  const int Mi_pad = (Mi + 127) & ~127;
  for (int g = Mt + tid; g < Mt_pad; g += 256) rowid[g] = -1;
  for (int g = Mt_pad + Mi + tid; g < Mt_pad + Mi_pad; g += 256) rowid[g] = -1;
  if (tid == 0) {
    ctrl[0] = Mt; ctrl[1] = Mt_pad; ctrl[2] = Mi; ctrl[3] = Mi_pad;
    ctrl[4] = Mt_pad + Mi_pad;
  }
}

// ---------------------------------------------------------------------------
// Weight transpose + fp32->bf16: W[k][n] -> WT[n][k] (B^T layout for GEMM)
// ---------------------------------------------------------------------------
__global__ __launch_bounds__(256) void transpose_to_bf16(
    const float* __restrict__ W, __hip_bfloat16* __restrict__ WT) {
  __shared__ float tile[32][33];
  const int bx = blockIdx.x, by = blockIdx.y;
  const int tid = threadIdx.x;
  const int r = tid >> 3, c4 = (tid & 7) * 4;
  const float4 v = *(const float4*)(W + (size_t)(by * 32 + r) * H_DIM + bx * 32 + c4);
  tile[r][c4 + 0] = v.x; tile[r][c4 + 1] = v.y;
  tile[r][c4 + 2] = v.z; tile[r][c4 + 3] = v.w;
  __syncthreads();
  union { ushort u[4]; ushort4 v4; } pk;
#pragma unroll
  for (int j = 0; j < 4; ++j) {
    __hip_bfloat16 h = __float2bfloat16(tile[c4 + j][r]);
    pk.u[j] = *(const ushort*)&h;
  }
  *(ushort4*)(WT + (size_t)(bx * 32 + r) * H_DIM + by * 32 + c4) = pk.v4;
}

// ---------------------------------------------------------------------------
// LayerNorm (fp32) -> bf16, scatter row to its gathered position.
// ---------------------------------------------------------------------------
__global__ __launch_bounds__(256) void ln_scatter_kernel(
    const float* __restrict__ X, const float* __restrict__ gamma,
    const float* __restrict__ beta, const int* __restrict__ pos,
    __hip_bfloat16* __restrict__ XG) {
  const int t = blockIdx.x, tid = threadIdx.x;
  const float* row = X + (size_t)t * H_DIM;
  float x[8];
  {
    float4 v0 = *(const float4*)(row + tid * 8);
    float4 v1 = *(const float4*)(row + tid * 8 + 4);
    x[0] = v0.x; x[1] = v0.y; x[2] = v0.z; x[3] = v0.w;
    x[4] = v1.x; x[5] = v1.y; x[6] = v1.z; x[7] = v1.w;
  }
  float s = 0.f, q = 0.f;
#pragma unroll
  for (int j = 0; j < 8; ++j) { s += x[j]; q += x[j] * x[j]; }
#pragma unroll
  for (int off = 32; off > 0; off >>= 1) {
    s += __shfl_down(s, off);
    q += __shfl_down(q, off);
  }
  __shared__ float ls[4], lq[4];
  if ((tid & 63) == 0) { ls[tid >> 6] = s; lq[tid >> 6] = q; }
  __syncthreads();
  const float S = ls[0] + ls[1] + ls[2] + ls[3];
  const float Q = lq[0] + lq[1] + lq[2] + lq[3];
  const float mu = S * (1.0f / H_DIM);
  const float var = Q * (1.0f / H_DIM) - mu * mu;
  const float rstd = rsqrtf(var + 1e-12f);
  const int p = pos[t];
  float4 g0 = *(const float4*)(gamma + tid * 8);
  float4 g1 = *(const float4*)(gamma + tid * 8 + 4);
  float4 b0 = *(const float4*)(beta + tid * 8);
  float4 b1 = *(const float4*)(beta + tid * 8 + 4);
  float g[8] = {g0.x, g0.y, g0.z, g0.w, g1.x, g1.y, g1.z, g1.w};
  float b[8] = {b0.x, b0.y, b0.z, b0.w, b1.x, b1.y, b1.z, b1.w};
  union { ushort u[8]; int4 v; } pk;
#pragma unroll
  for (int j = 0; j < 8; ++j) {
    float y = (x[j] - mu) * rstd * g[j] + b[j];
    __hip_bfloat16 h = __float2bfloat16(y);
    pk.u[j] = *(const ushort*)&h;
  }
  *(int4*)(XG + (size_t)p * H_DIM + tid * 8) = pk.v;
}

// --- asm helpers for the GEMM inner loop -----------------------------------
#define DSRD(dst, addr, OFF) \
  asm volatile("ds_read_b128 %0, %1 offset:" OFF : "=v"(dst) : "v"(addr))
#define PBAR asm volatile("s_barrier" ::: "memory")
#define SB0  __builtin_amdgcn_sched_barrier(0)
#define LGKM0 do { \
  asm volatile("s_waitcnt lgkmcnt(0)" ::: "memory"); SB0; } while (0)
#define VM0 asm volatile("s_waitcnt vmcnt(0)" ::: "memory")

// ---------------------------------------------------------------------------
// 4-wave 128x128 GEMM (R1 geometry), BK=32. 256 thr = 4 waves (wm=w>>1,
// wn=w&1), per-wave 64x64 = acc[4][4] frags of 16x16x32 (64 AGPR; total
// ~125 regs/thread -> 3-4 blocks/CU, no cap, NO SPILL).
// LDS 32 KiB: Alds/Blds [2 buf][64 macro-rows][64 elems]; macro-row mr packs
// rows {2mr,2mr+1} x 32 k as 8 granules of 8 elems, granule g at position
// g^(mr&7) (conflict-free ds_read_b128; element-traced in R6 post-mortem).
// Staging realizes the swizzle via pre-swizzled GLOBAL source + linear LDS
// dest (rule #21). Loop: stage(next)->reads->lgkm0->16 MFMA->vm0->barrier.
// Cross-wave hazards: reads of buf c retire (lgkm0) before end-of-t barrier;
// stage of buf c happens after that barrier at t+1; staged data drained by
// vm0+barrier before its reads at t+1.
// ---------------------------------------------------------------------------
template <int EPI>
__global__ __launch_bounds__(256, 2) void gemmk(
    const __hip_bfloat16* __restrict__ A,
    const __hip_bfloat16* __restrict__ WTt, const __hip_bfloat16* __restrict__ WTi,
    const float* __restrict__ bt, const float* __restrict__ bi,
    const int* __restrict__ ctrl, const int* __restrict__ rowid,
    __hip_bfloat16* __restrict__ Hout,
    const float* __restrict__ resid, float* __restrict__ Out) {
  constexpr int K = H_DIM;
  constexpr int NT = K / 32;            // 64 K-tiles
  const int Mt_pad = ctrl[1];
  const int total = ctrl[4];
  // 1056 blocks = 8 XCD-groups x 132 (= 66 tiles x 2 N-cols): each XCD works
  // 2 N-panels -> B working set 2 MB, L2-resident.
  const int bid = blockIdx.x;
  const int swz = (bid & 7) * 132 + (bid >> 3);
  const int m0 = (swz % 66) * 128;
  const int n0 = (swz / 66) * 128;
  if (m0 >= total) return;
  const bool is_text = (m0 < Mt_pad);
  const short* Ag = (const short*)A;
  const short* Bg = (const short*)(is_text ? WTt : WTi);
  const float* bias = is_text ? bt : bi;

  __shared__ __align__(16) short Alds[2][4096];   // [buf][64 mr * 64] = 8 KiB
  __shared__ __align__(16) short Blds[2][4096];

  const int tid = threadIdx.x;
  const int w = tid >> 6, l = tid & 63;           // 4 waves
  const int wm = w >> 1, wn = w & 1;

  // ---- staging lane constants (pre-swizzled global source)
  const int srow8 = l >> 3;               // macro-row within this lane-set's 8
  const int sg = (l & 7) ^ srow8;         // granule fetched for position l&7
  const int sRowAdj = sg >> 2;            // row parity within macro-row
  const int sKAdj = (sg & 3) * 8;         // k offset 0..24

  // stage half c2 (32 macro-rows = 4KB) of A/B K-tile kk into buf bI
  auto stageA = [&](int bI, int c2, int kk) {
    const int mr = c2 * 32 + w * 8 + srow8;
    const short* src = Ag + (size_t)(m0 + mr * 2 + sRowAdj) * K + kk + sKAdj;
    load_lds16(src, &Alds[bI][(c2 * 32 + w * 8) * 64]);
  };
  auto stageB = [&](int bI, int c2, int kk) {
    const int mr = c2 * 32 + w * 8 + srow8;
    const short* src = Bg + (size_t)(n0 + mr * 2 + sRowAdj) * K + kk + sKAdj;
    load_lds16(src, &Blds[bI][(c2 * 32 + w * 8) * 64]);
  };

  // ---- read addressing: frag f rows wm*64+f*16+(l&15), k-chunk l>>4.
  // macro-row = wm*32 + f*8 + hl (mr&7 = hl); granule = (l&1)*4 + (l>>4);
  // position = granule ^ hl. frag f at literal byte offset f*1024.
  const int hl = (l & 15) >> 1;
  const int gr = (((l & 1) << 2) | (l >> 4)) ^ hl;
  const unsigned aBase = (unsigned)(uintptr_t)(lds_s*)&Alds[0][0];
  const unsigned bBase = (unsigned)(uintptr_t)(lds_s*)&Blds[0][0];
  unsigned ardA[2], ardB[2];
#pragma unroll
  for (int bI = 0; bI < 2; ++bI) {
    ardA[bI] = aBase + bI * 8192u + (unsigned)(wm * 4096 + hl * 128 + gr * 16);
    ardB[bI] = bBase + bI * 8192u + (unsigned)(wn * 4096 + hl * 128 + gr * 16);
  }

  i32x4 a[4], b[4];
  f32x4 acc[4][4];
  const f32x4 zero = {0.f, 0.f, 0.f, 0.f};
#pragma unroll
  for (int i = 0; i < 4; ++i)
#pragma unroll
    for (int j = 0; j < 4; ++j) acc[i][j] = zero;

#define RD_TILE(C) do {                                                   \
    DSRD(a[0], ardA[C], "0");    DSRD(a[1], ardA[C], "1024");             \
    DSRD(a[2], ardA[C], "2048"); DSRD(a[3], ardA[C], "3072");             \
    DSRD(b[0], ardB[C], "0");    DSRD(b[1], ardB[C], "1024");             \
    DSRD(b[2], ardB[C], "2048"); DSRD(b[3], ardB[C], "3072");             \
  } while (0)

  // prologue: stage tile 0 into buf 0
  stageA(0, 0, 0); stageA(0, 1, 0);
  stageB(0, 0, 0); stageB(0, 1, 0);
  VM0;
  PBAR;

  for (int t = 0; t < NT; ++t) {
    const int c = t & 1;
    const int kn = (t + 1 < NT ? t + 1 : NT - 1) * 32;
    // issue next-tile staging first (HBM latency hides under reads+MFMA)
    stageA(c ^ 1, 0, kn); stageA(c ^ 1, 1, kn);
    stageB(c ^ 1, 0, kn); stageB(c ^ 1, 1, kn);
    RD_TILE(c);
    LGKM0;   // asm outputs a[]/b[] valid from here (no spill: ~125 regs, no cap)
    __builtin_amdgcn_s_setprio(1);
#pragma unroll
    for (int f = 0; f < 4; ++f)
#pragma unroll
      for (int fn = 0; fn < 4; ++fn)
        acc[f][fn] = __builtin_amdgcn_mfma_f32_16x16x32_bf16(
            asbf(a[f]), asbf(b[fn]), acc[f][fn], 0, 0, 0);
    __builtin_amdgcn_s_setprio(0);
    SB0;
    VM0;   // this wave's staging landed
    PBAR;  // all waves: reads of buf c retired + staging of buf c^1 landed
  }
#undef RD_TILE

  // epilogue: C/D layout col=lane&15, row=(lane>>4)*4+i  [R1-verified]
  const int r16 = l & 15, r4base = (l >> 4) * 4;
  if (EPI == 0) {
    float bb[4];
#pragma unroll
    for (int fn = 0; fn < 4; ++fn) bb[fn] = bias[n0 + wn * 64 + fn * 16 + r16];
#pragma unroll
    for (int fm = 0; fm < 4; ++fm) {
      const int grow = m0 + wm * 64 + fm * 16 + r4base;
#pragma unroll
      for (int fn = 0; fn < 4; ++fn) {
        const int gcol = n0 + wn * 64 + fn * 16 + r16;
        f32x4 v = acc[fm][fn];
#pragma unroll
        for (int i = 0; i < 4; ++i) {
          float z = v[i] + bb[fn];
          float ge = 0.5f * z * (1.0f + erff(z * 0.70710678118654752f));
          Hout[(size_t)(grow + i) * K + gcol] = __float2bfloat16(ge);
        }
      }
    }
  } else {
    float bb[4];
#pragma unroll
    for (int fn = 0; fn < 4; ++fn) bb[fn] = bias[n0 + wn * 64 + fn * 16 + r16];
#pragma unroll
    for (int fm = 0; fm < 4; ++fm) {
      const int grow = m0 + wm * 64 + fm * 16 + r4base;
      int rid[4];
#pragma unroll
      for (int i = 0; i < 4; ++i) rid[i] = rowid[grow + i];
#pragma unroll
      for (int fn = 0; fn < 4; ++fn) {
        const int gcol = n0 + wn * 64 + fn * 16 + r16;
        f32x4 v = acc[fm][fn];
#pragma unroll
        for (int i = 0; i < 4; ++i) {
          if (rid[i] >= 0) {
            const size_t o = (size_t)rid[i] * K + gcol;
            Out[o] = resid[o] + v[i] + bb[fn];
          }
        }
      }
    }
  }
}

// ---------------------------------------------------------------------------
extern "C" void kernel_launch(void* const* d_in, const int* in_sizes, int n_in,
                              void* d_out, int out_size, void* d_ws, size_t ws_size,
                              hipStream_t stream) {
  const float* hidden = (const float*)d_in[0];
  const int*   tt     = (const int*)d_in[1];
  const float* gamma  = (const float*)d_in[2];
  const float* beta   = (const float*)d_in[3];
  const float* tw1    = (const float*)d_in[4];
  const float* tb1    = (const float*)d_in[5];
  const float* tw2    = (const float*)d_in[6];
  const float* tb2    = (const float*)d_in[7];
  const float* iw1    = (const float*)d_in[8];
  const float* ib1    = (const float*)d_in[9];
  const float* iw2    = (const float*)d_in[10];
  const float* ib2    = (const float*)d_in[11];
  float* out = (float*)d_out;

  const int T = in_sizes[1];          // 8192 tokens
  const int K = H_DIM;
  const int maxtiles = T / 128 + 2;   // groups padded to 128 -> 66 tiles
  const int maxrows = maxtiles * 128;

  char* ws = (char*)d_ws;
  int* ctrl  = (int*)(ws);
  int* pos   = (int*)(ws + 4096);
  int* rowid = (int*)(ws + 65536);
  const size_t WOFF = 131072;
  const size_t WSZ = (size_t)K * K * sizeof(__hip_bfloat16);
  __hip_bfloat16* tw1T = (__hip_bfloat16*)(ws + WOFF);
  __hip_bfloat16* tw2T = (__hip_bfloat16*)(ws + WOFF + WSZ);
  __hip_bfloat16* iw1T = (__hip_bfloat16*)(ws + WOFF + 2 * WSZ);
  __hip_bfloat16* iw2T = (__hip_bfloat16*)(ws + WOFF + 3 * WSZ);
  __hip_bfloat16* xg   = (__hip_bfloat16*)(ws + WOFF + 4 * WSZ);
  __hip_bfloat16* hb   = xg + (size_t)maxrows * K;

  hipMemsetAsync(xg, 0, (size_t)maxrows * K * sizeof(__hip_bfloat16), stream);

  partition_kernel<<<1, 256, 0, stream>>>(tt, T, ctrl, pos, rowid);

  dim3 tg(K / 32, K / 32);
  transpose_to_bf16<<<tg, 256, 0, stream>>>(tw1, tw1T);
  transpose_to_bf16<<<tg, 256, 0, stream>>>(tw2, tw2T);
  transpose_to_bf16<<<tg, 256, 0, stream>>>(iw1, iw1T);
  transpose_to_bf16<<<tg, 256, 0, stream>>>(iw2, iw2T);

  ln_scatter_kernel<<<T, 256, 0, stream>>>(hidden, gamma, beta, pos, xg);

  const int nblk = maxtiles * (K / 128);   // 66 * 16 = 1056
  gemmk<0><<<nblk, 256, 0, stream>>>(xg, tw1T, iw1T, tb1, ib1, ctrl, rowid,
                                     hb, nullptr, nullptr);
  gemmk<1><<<nblk, 256, 0, stream>>>(hb, tw2T, iw2T, tb2, ib2, ctrl, rowid,
                                     nullptr, hidden, out);
}